// Round 1
// baseline (114.524 us; speedup 1.0000x reference)
//
#include <hip/hip_runtime.h>

// Lin2d: x_final = x @ (linMt)^N.  The N-step recurrence is a single linear
// map, so we compute M = linMt^N once (binary exponentiation, fp32 — error
// ~1e-6 rel vs 1.08e-1 threshold) and do one memory-bound streaming pass.
// Traffic: 64 MiB read + 64 MiB write -> ~21 us floor at 6.3 TB/s.

__global__ __launch_bounds__(256)
void lin2d_apply(const float* __restrict__ x,
                 const float* __restrict__ linMt,
                 const int* __restrict__ Nptr,
                 float* __restrict__ out,
                 long long n4, long long ntail_pairs)
{
    // A = linMt row-major 2x2.  y = x @ A  =>  y_j = x0*A[0][j] + x1*A[1][j].
    float b00 = linMt[0], b01 = linMt[1];
    float b10 = linMt[2], b11 = linMt[3];
    unsigned e = (unsigned)Nptr[0];

    // M = A^e via binary exponentiation (each thread redundantly; ~80 FMAs,
    // hidden behind memory waits in this HBM-bound kernel).
    float r00 = 1.f, r01 = 0.f, r10 = 0.f, r11 = 1.f;
    while (e) {
        if (e & 1u) {
            float t00 = r00*b00 + r01*b10;
            float t01 = r00*b01 + r01*b11;
            float t10 = r10*b00 + r11*b10;
            float t11 = r10*b01 + r11*b11;
            r00 = t00; r01 = t01; r10 = t10; r11 = t11;
        }
        e >>= 1;
        if (e) {
            float t00 = b00*b00 + b01*b10;
            float t01 = b00*b01 + b01*b11;
            float t10 = b10*b00 + b11*b10;
            float t11 = b10*b01 + b11*b11;
            b00 = t00; b01 = t01; b10 = t10; b11 = t11;
        }
    }

    // Streaming apply: one float4 = two 2-d states. Coalesced 16B/lane.
    const float4* __restrict__ xin = (const float4*)x;
    float4* __restrict__ o = (float4*)out;
    long long idx    = (long long)blockIdx.x * blockDim.x + threadIdx.x;
    long long stride = (long long)gridDim.x * blockDim.x;
    for (long long i = idx; i < n4; i += stride) {
        float4 v = xin[i];
        float4 w;
        w.x = v.x * r00 + v.y * r10;
        w.y = v.x * r01 + v.y * r11;
        w.z = v.z * r00 + v.w * r10;
        w.w = v.z * r01 + v.w * r11;
        o[i] = w;
    }

    // Tail (total floats not divisible by 4) — handled scalar by one thread.
    if (idx == 0) {
        for (long long p = 0; p < ntail_pairs; ++p) {
            long long base = n4 * 4 + p * 2;
            float x0 = x[base], x1 = x[base + 1];
            out[base]     = x0 * r00 + x1 * r10;
            out[base + 1] = x0 * r01 + x1 * r11;
        }
    }
}

extern "C" void kernel_launch(void* const* d_in, const int* in_sizes, int n_in,
                              void* d_out, int out_size, void* d_ws, size_t ws_size,
                              hipStream_t stream) {
    const float* x     = (const float*)d_in[0];   // (B, 2) fp32, flat
    const float* linMt = (const float*)d_in[1];   // 2x2 fp32
    const int*   N     = (const int*)d_in[2];     // scalar int as 1-elem array
    float* out = (float*)d_out;

    long long total = (long long)in_sizes[0];     // B*2 floats
    long long n4 = total / 4;                     // float4 chunks (2 states each)
    long long ntail_pairs = (total - n4 * 4) / 2;

    // 4096 blocks x 256 threads = 1M threads; ~4 float4 iters each via
    // grid-stride. Plenty of waves to saturate 256 CUs on a streaming op.
    lin2d_apply<<<4096, 256, 0, stream>>>(x, linMt, N, out, n4, ntail_pairs);
}